// Round 7
// baseline (4382.607 us; speedup 1.0000x reference)
//
#include <hip/hip_runtime.h>
#include <math.h>

// Problem dims
constexpr int Bsz  = 512;
constexpr int Nseq = 64;
constexpr int DX   = 4;
constexpr int MET  = 4;
constexpr int Hd   = 512;
constexpr int H3d  = 1536;

constexpr float RTOL_C = 1e-3f;
constexpr float ATOL_C = 1e-5f;

// ---- Dopri5 tableau (exactly as in jax.experimental.ode, f64->f32) ----
constexpr float SB10 = (float)(1.0/5.0);
constexpr float SB20 = (float)(3.0/40.0),  SB21 = (float)(9.0/40.0);
constexpr float SB30 = (float)(44.0/45.0), SB31 = (float)(-56.0/15.0), SB32 = (float)(32.0/9.0);
constexpr float SB40 = (float)(19372.0/6561.0), SB41 = (float)(-25360.0/2187.0),
                SB42 = (float)(64448.0/6561.0), SB43 = (float)(-212.0/729.0);
constexpr float SB50 = (float)(9017.0/3168.0),  SB51 = (float)(-355.0/33.0),
                SB52 = (float)(46732.0/5247.0), SB53 = (float)(49.0/176.0),
                SB54 = (float)(-5103.0/18656.0);
constexpr float CS0 = (float)(35.0/384.0), CS2 = (float)(500.0/1113.0),
                CS3 = (float)(125.0/192.0), CS4 = (float)(-2187.0/6784.0),
                CS5 = (float)(11.0/84.0);
// Shampine error coefficients (c_sol - c_star), as written in jax ode.py
constexpr float CE0 = (float)(35.0/384.0 - 1951.0/21600.0);
constexpr float CE2 = (float)(500.0/1113.0 - 22642.0/50085.0);
constexpr float CE3 = (float)(125.0/192.0 - 451.0/720.0);
constexpr float CE4 = (float)(-2187.0/6784.0 + 12231.0/42400.0);
constexpr float CE5 = (float)(11.0/84.0 - 649.0/6300.0);
constexpr float CE6 = (float)(-1.0/60.0);
// dps_c_mid for interpolation fit
constexpr float CM0 = (float)(6025192743.0/30085553152.0/2.0);
constexpr float CM2 = (float)(51252292925.0/65400821598.0/2.0);
constexpr float CM3 = (float)(-2691868925.0/45128329728.0/2.0);
constexpr float CM4 = (float)(187940372067.0/1594534317056.0/2.0);
constexpr float CM5 = (float)(-1776094331.0/19743644256.0/2.0);
constexpr float CM6 = (float)(11237099.0/235043384.0/2.0);

__device__ __forceinline__ float selu_f(float v) {
  const float scl = 1.0507009873554805f;
  const float alp = 1.6732632423543772f;
  float e = v > 0.f ? v : alp * expm1f(v);
  return scl * e;
}
__device__ __forceinline__ float sigmoid_f(float v) {
  return 1.f / (1.f + expf(-v));
}

// ---------------- weight repack kernels ----------------
// W: (R,K) row-major -> P[k/4][R][4] so inner k-loop uses one float4/row
__global__ void pack_kT4(const float* __restrict__ W, float* __restrict__ P, int R, int K) {
  int i = blockIdx.x * 256 + threadIdx.x;
  if (i >= R * K) return;
  int r = i / K, k = i % K;
  P[(k >> 2) * (R * 4) + r * 4 + (k & 3)] = W[i];
}
// plain transpose (R,C) -> (C,R)
__global__ void transpose_k(const float* __restrict__ W, float* __restrict__ T, int R, int C) {
  int i = blockIdx.x * 256 + threadIdx.x;
  if (i >= R * C) return;
  int r = i / C, c = i % C;
  T[c * R + r] = W[i];
}

// ---------------- persistent cooperative GRU, lightweight barrier ----------------
// 256 blocks x 512 threads (1/CU). Block = 16 batch rows x 64 j-cols;
// jt = bid>>5 keeps each XCD's 32 blocks on ONE 393KB weight slice (R4-proven).
// Cross-XCD h exchange uses agent-scope atomics (write-through stores; loads
// bypass L1/L2 and read the coherence point) -> NO cache invalidation and NO
// L2 writeback at the barrier. Barrier = monotonic counter: syncthreads
// (drains all waves' stores, compiler emits vmcnt(0)) -> tid0 release
// fetch_add -> relaxed spin -> syncthreads. W/x/bias stay warm in L1/L2.
// (R4's cg::grid.sync cost ~55us/step: WRITE_SIZE 66MB showed a full L2
//  writeback per step. This removes it. Per-(b,j) math identical -> h bitwise
//  identical to the per-step-launch version.)
__global__ __launch_bounds__(512) void gru_coop2_kernel(
    const float* __restrict__ x, const float* __restrict__ meta,
    const float* __restrict__ WihT, const float* __restrict__ WhhP,
    const float* __restrict__ bih, const float* __restrict__ bhh,
    float* __restrict__ hA, float* __restrict__ hB,
    unsigned* __restrict__ bar)
{
  __shared__ __align__(16) float hs[16][Hd];         // 32 KB: h[t] tile
  __shared__ __align__(16) float xs[16][Nseq * DX];  // 16 KB: x rows, staged once
  const int tid = threadIdx.x;
  const int jl  = tid & 63;
  const int rg  = tid >> 6;                          // wave 0..7 -> rows 2rg,2rg+1
  const int jt  = (int)(blockIdx.x >> 5);            // j-tile == XCD (depth-first)
  const int bt  = (int)(blockIdx.x & 31);
  const int j   = jt * 64 + jl;
  const int b0  = bt * 16;
  const int nb  = (int)gridDim.x;                    // 256

  // stage x rows once (16 rows x 256 floats)
  for (int i = tid; i < 16 * Nseq; i += 512) {
    const int r = i >> 6, c = i & 63;
    *(float4*)&xs[r][c * 4] = *(const float4*)&x[(b0 + r) * (Nseq * DX) + c * 4];
  }
  // h0 = 0 in LDS
  for (int i = tid; i < 16 * Hd; i += 512) ((float*)hs)[i] = 0.f;

  // cache input-projection weights + biases + meta in registers
  float wir[8], wiz[8], win[8];
#pragma unroll
  for (int kk = 0; kk < 8; ++kk) {
    wir[kk] = WihT[kk * H3d + j];
    wiz[kk] = WihT[kk * H3d + 512 + j];
    win[kk] = WihT[kk * H3d + 1024 + j];
  }
  const float bihr = bih[j], bihz = bih[512 + j], bihn = bih[1024 + j];
  const float bhhr = bhh[j], bhhz = bhh[512 + j], bhhn = bhh[1024 + j];
  const float4 mv0 = *(const float4*)&meta[(b0 + rg * 2 + 0) * MET];
  const float4 mv1 = *(const float4*)&meta[(b0 + rg * 2 + 1) * MET];

  __syncthreads();

  for (int t = 0; t < Nseq; ++t) {
    float ar0 = 0.f, az0 = 0.f, an0 = 0.f;
    float ar1 = 0.f, az1 = 0.f, an1 = 0.f;
#pragma unroll 4
    for (int k4 = 0; k4 < Hd / 4; ++k4) {
      const float4 wr = *(const float4*)&WhhP[(k4 * H3d + j) * 4];
      const float4 wz = *(const float4*)&WhhP[(k4 * H3d + 512 + j) * 4];
      const float4 wn = *(const float4*)&WhhP[(k4 * H3d + 1024 + j) * 4];
      const float4 h0 = *(const float4*)&hs[rg * 2 + 0][k4 * 4];   // broadcast
      const float4 h1 = *(const float4*)&hs[rg * 2 + 1][k4 * 4];
      ar0 += wr.x * h0.x + wr.y * h0.y + wr.z * h0.z + wr.w * h0.w;
      az0 += wz.x * h0.x + wz.y * h0.y + wz.z * h0.z + wz.w * h0.w;
      an0 += wn.x * h0.x + wn.y * h0.y + wn.z * h0.z + wn.w * h0.w;
      ar1 += wr.x * h1.x + wr.y * h1.y + wr.z * h1.z + wr.w * h1.w;
      az1 += wz.x * h1.x + wz.y * h1.y + wz.z * h1.z + wz.w * h1.w;
      an1 += wn.x * h1.x + wn.y * h1.y + wn.z * h1.z + wn.w * h1.w;
    }

    float* hcur = (t & 1) ? hB : hA;
#pragma unroll
    for (int m = 0; m < 2; ++m) {
      const int bl = rg * 2 + m;
      const int b  = b0 + bl;
      const float4 xv = *(const float4*)&xs[bl][t * 4];
      const float4 mv = m ? mv1 : mv0;
      float xm[8] = { xv.x, xv.y, xv.z, xv.w, mv.x, mv.y, mv.z, mv.w };
      float gr = bihr, gz = bihz, gn = bihn;
#pragma unroll
      for (int kk = 0; kk < 8; ++kk) {
        gr += xm[kk] * wir[kk];
        gz += xm[kk] * wiz[kk];
        gn += xm[kk] * win[kk];
      }
      const float ghr = (m ? ar1 : ar0) + bhhr;
      const float ghz = (m ? az1 : az0) + bhhz;
      const float ghn = (m ? an1 : an0) + bhhn;
      const float r = sigmoid_f(gr + ghr);
      const float z = sigmoid_f(gz + ghz);
      const float n = tanhf(gn + r * ghn);
      const float hold = hs[bl][j];
      const float hval = (1.f - z) * n + z * hold;
      // agent-scope write-through: visible at the device coherence point
      __hip_atomic_store(&hcur[b * Hd + j], hval, __ATOMIC_RELAXED,
                         __HIP_MEMORY_SCOPE_AGENT);
    }

    if (t == Nseq - 1) break;

    __syncthreads();   // all waves' stores drained (vmcnt(0)) + hs reads done
    if (tid == 0) {
      __hip_atomic_fetch_add(bar, 1u, __ATOMIC_RELEASE, __HIP_MEMORY_SCOPE_AGENT);
      const unsigned tgt = (unsigned)nb * (unsigned)(t + 1);
      while (__hip_atomic_load(bar, __ATOMIC_RELAXED, __HIP_MEMORY_SCOPE_AGENT) < tgt) {
        __builtin_amdgcn_s_sleep(2);
      }
    }
    __syncthreads();

    // restage h[t+1] tile; agent-scope loads bypass caches -> always fresh
    const unsigned long long* src =
        (const unsigned long long*)(hcur + (size_t)b0 * Hd);
    unsigned long long* dst = (unsigned long long*)&hs[0][0];
    for (int i = tid; i < 16 * Hd / 2; i += 512) {
      dst[i] = __hip_atomic_load(&src[i], __ATOMIC_RELAXED,
                                 __HIP_MEMORY_SCOPE_AGENT);
    }
    __syncthreads();
  }
}

// ---------------- encoder layer 1: relu(A @ W^T + b) ----------------
__global__ __launch_bounds__(256) void gemm_relu_kernel(
    const float* __restrict__ A, const float* __restrict__ WP,
    const float* __restrict__ bias, float* __restrict__ Cout)
{
  __shared__ __align__(16) float as[16 * Hd];
  const int tid  = threadIdx.x;
  const int jl   = tid & 63;
  const int bsub = tid >> 6;
  const int j    = blockIdx.y * 64 + jl;
  const int b0   = blockIdx.x * 16;

  for (int i = tid; i < 16 * Hd; i += 256) as[i] = A[b0 * Hd + i];
  __syncthreads();

  float acc[4] = {0.f, 0.f, 0.f, 0.f};
#pragma unroll 2
  for (int k4 = 0; k4 < Hd / 4; ++k4) {
    const float4 w = *(const float4*)&WP[(k4 * Hd + j) * 4];
#pragma unroll
    for (int m = 0; m < 4; ++m) {
      const float4 av = *(const float4*)&as[(bsub * 4 + m) * Hd + k4 * 4];
      acc[m] += w.x * av.x + w.y * av.y + w.z * av.z + w.w * av.w;
    }
  }
  const float bj = bias[j];
#pragma unroll
  for (int m = 0; m < 4; ++m) {
    const int b = b0 + bsub * 4 + m;
    float v = acc[m] + bj;
    Cout[b * Hd + j] = v > 0.f ? v : 0.f;
  }
}

// ---------------- encoder layer 2 + reparam: z0 = eps*std + mean ----------------
__global__ __launch_bounds__(256) void enc2_z0_kernel(
    const float* __restrict__ O1, const float* __restrict__ W2P,  // [k4][1024][4]
    const float* __restrict__ b2, const float* __restrict__ eps,
    float* __restrict__ z0)
{
  __shared__ __align__(16) float as[16 * Hd];
  const int tid  = threadIdx.x;
  const int jl   = tid & 63;
  const int bsub = tid >> 6;
  const int j    = blockIdx.y * 64 + jl;
  const int b0   = blockIdx.x * 16;

  for (int i = tid; i < 16 * Hd; i += 256) as[i] = O1[b0 * Hd + i];
  __syncthreads();

  float am[4] = {0.f, 0.f, 0.f, 0.f};
  float asd[4] = {0.f, 0.f, 0.f, 0.f};
#pragma unroll 2
  for (int k4 = 0; k4 < Hd / 4; ++k4) {
    const float4 wm = *(const float4*)&W2P[(k4 * 1024 + j) * 4];
    const float4 ws = *(const float4*)&W2P[(k4 * 1024 + 512 + j) * 4];
#pragma unroll
    for (int m = 0; m < 4; ++m) {
      const float4 av = *(const float4*)&as[(bsub * 4 + m) * Hd + k4 * 4];
      am[m]  += wm.x * av.x + wm.y * av.y + wm.z * av.z + wm.w * av.w;
      asd[m] += ws.x * av.x + ws.y * av.y + ws.z * av.z + ws.w * av.w;
    }
  }
  const float bm = b2[j], bs = b2[512 + j];
#pragma unroll
  for (int m = 0; m < 4; ++m) {
    const int b = b0 + bsub * 4 + m;
    const float mean = am[m] + bm;
    const float sd   = asd[m] + bs;
    z0[b * Hd + j] = eps[b * Hd + j] * sd + mean;
  }
}

// ---------------- adaptive Dopri5 ODE solve + final FC ----------------
// 256 blocks x 512 threads, GE=2. At ~92% of the L2-BW roofline for the
// weight stream (34GB @ 34.5TB/s ~= 0.98ms vs 1.08 measured) -- unchanged.
__global__ __launch_bounds__(512) void ode_fc_kernel(
    const float* __restrict__ x, const float* __restrict__ meta,
    const float* __restrict__ z0in,
    const float* __restrict__ W1P, const float* __restrict__ b1v,
    const float* __restrict__ W2P, const float* __restrict__ b2v,
    const float* __restrict__ fcW, const float* __restrict__ fcb,
    float* __restrict__ outp)
{
  constexpr int GE = 2;
  __shared__ __align__(16) float zsh[GE][Hd];   // 4 KB
  __shared__ float red[8 * GE];
  const int tid = threadIdx.x;
  const int jj  = tid & 255;
  const int eh  = tid >> 8;            // element 0/1 (wave-uniform)
  const int j1  = jj + 256;
  const int bg0 = blockIdx.x * GE;

  const float b1a = b1v[jj], b1b = b1v[j1];
  const float b2a = b2v[jj], b2b = b2v[j1];

  // drift for the thread's 2 (j, eh) slots
  auto drift = [&](const float (&in)[2], float (&out)[2]) {
    __syncthreads();
    zsh[eh][jj] = in[0];
    zsh[eh][j1] = in[1];
    __syncthreads();
    float u0 = b1a, u1 = b1b;
#pragma unroll 4
    for (int k4 = 0; k4 < Hd / 4; ++k4) {
      const float4 wA = *(const float4*)&W1P[(k4 * Hd + jj) * 4];
      const float4 wB = *(const float4*)&W1P[(k4 * Hd + j1) * 4];
      const float4 z  = *(const float4*)&zsh[eh][k4 * 4];
      u0 += wA.x * z.x + wA.y * z.y + wA.z * z.z + wA.w * z.w;
      u1 += wB.x * z.x + wB.y * z.y + wB.z * z.z + wB.w * z.w;
    }
    u0 = selu_f(u0); u1 = selu_f(u1);
    __syncthreads();
    zsh[eh][jj] = u0;
    zsh[eh][j1] = u1;
    __syncthreads();
    float v0 = b2a, v1 = b2b;
#pragma unroll 4
    for (int k4 = 0; k4 < Hd / 4; ++k4) {
      const float4 wA = *(const float4*)&W2P[(k4 * Hd + jj) * 4];
      const float4 wB = *(const float4*)&W2P[(k4 * Hd + j1) * 4];
      const float4 z  = *(const float4*)&zsh[eh][k4 * 4];
      v0 += wA.x * z.x + wA.y * z.y + wA.z * z.z + wA.w * z.w;
      v1 += wB.x * z.x + wB.y * z.y + wB.z * z.z + wB.w * z.w;
    }
    out[0] = v0; out[1] = v1;
  };

  // block-wide per-element sum; all threads receive identical results
  auto blocksum = [&](float (&v)[GE], float (&s)[GE]) {
#pragma unroll
    for (int off = 32; off > 0; off >>= 1) {
#pragma unroll
      for (int g = 0; g < GE; ++g) v[g] += __shfl_down(v[g], off);
    }
    __syncthreads();
    if ((tid & 63) == 0) {
      const int w = tid >> 6;
#pragma unroll
      for (int g = 0; g < GE; ++g) red[w * GE + g] = v[g];
    }
    __syncthreads();
#pragma unroll
    for (int g = 0; g < GE; ++g) {
      float t = 0.f;
#pragma unroll
      for (int w = 0; w < 8; ++w) t += red[w * GE + g];
      s[g] = t;
    }
  };

  float y[2], f[2], py[2], pf[2], ym[2];
  float tcur[GE], dtv[GE], tfin[GE], ptv[GE], pdt[GE];
  bool act[GE];

  y[0] = z0in[(bg0 + eh) * Hd + jj];
  y[1] = z0in[(bg0 + eh) * Hd + j1];
#pragma unroll
  for (int g = 0; g < GE; ++g) {
    tcur[g] = x[((bg0 + g) * Nseq + 0) * DX];
    tfin[g] = x[((bg0 + g) * Nseq + (Nseq - 1)) * DX];
  }

  drift(y, f);

  // ---- initial step size (Hairer / jax variant) ----
  float sc[2];
  float q0[GE] = {0.f, 0.f}, q1[GE] = {0.f, 0.f};
#pragma unroll
  for (int l = 0; l < 2; ++l) {
    sc[l] = ATOL_C + RTOL_C * fabsf(y[l]);
    const float a = y[l] / sc[l], b = f[l] / sc[l];
    q0[eh] += a * a;
    q1[eh] += b * b;
  }
  float d0s[GE], d1s[GE];
  blocksum(q0, d0s);
  blocksum(q1, d1s);
  float h0[GE];
#pragma unroll
  for (int g = 0; g < GE; ++g) {
    const float d0 = sqrtf(d0s[g]), d1 = sqrtf(d1s[g]);
    h0[g] = (d0 < 1e-5f || d1 < 1e-5f) ? 1e-6f : 0.01f * d0 / d1;
  }
  float yin[2], f1h[2];
#pragma unroll
  for (int l = 0; l < 2; ++l) yin[l] = y[l] + h0[eh] * f[l];
  drift(yin, f1h);
  float q2[GE] = {0.f, 0.f};
#pragma unroll
  for (int l = 0; l < 2; ++l) {
    const float dd = (f1h[l] - f[l]) / sc[l];
    q2[eh] += dd * dd;
  }
  float d2s[GE];
  blocksum(q2, d2s);
#pragma unroll
  for (int g = 0; g < GE; ++g) {
    const float d1 = sqrtf(d1s[g]);
    const float d2 = sqrtf(d2s[g]) / h0[g];
    const float h1 = (d1 <= 1e-15f && d2 <= 1e-15f)
                 ? fmaxf(1e-6f, h0[g] * 1e-3f)
                 : powf(0.01f / (d1 + d2), 0.2f);   // jax uses d1+d2 here
    dtv[g] = fminf(100.f * h0[g], h1);
    ptv[g] = tcur[g]; pdt[g] = dtv[g];
    act[g] = (tcur[g] < tfin[g]) && (dtv[g] > 0.f);
  }
#pragma unroll
  for (int l = 0; l < 2; ++l) { py[l] = y[l]; pf[l] = f[l]; ym[l] = y[l]; }

  // ---- adaptive stepping loop ----
  float k2[2], k3[2], k4v[2], k5[2], k6[2], k7[2], y1v[2];
  for (int iter = 0; iter < 4000; ++iter) {
    if (!(act[0] || act[1])) break;

#pragma unroll
    for (int l = 0; l < 2; ++l) yin[l] = y[l] + dtv[eh] * (SB10 * f[l]);
    drift(yin, k2);

#pragma unroll
    for (int l = 0; l < 2; ++l)
      yin[l] = y[l] + dtv[eh] * (SB20 * f[l] + SB21 * k2[l]);
    drift(yin, k3);

#pragma unroll
    for (int l = 0; l < 2; ++l)
      yin[l] = y[l] + dtv[eh] * (SB30 * f[l] + SB31 * k2[l] + SB32 * k3[l]);
    drift(yin, k4v);

#pragma unroll
    for (int l = 0; l < 2; ++l)
      yin[l] = y[l] + dtv[eh] * (SB40 * f[l] + SB41 * k2[l] + SB42 * k3[l] + SB43 * k4v[l]);
    drift(yin, k5);

#pragma unroll
    for (int l = 0; l < 2; ++l)
      yin[l] = y[l] + dtv[eh] * (SB50 * f[l] + SB51 * k2[l] + SB52 * k3[l] + SB53 * k4v[l] + SB54 * k5[l]);
    drift(yin, k6);

#pragma unroll
    for (int l = 0; l < 2; ++l)
      y1v[l] = y[l] + dtv[eh] * (CS0 * f[l] + CS2 * k3[l] + CS3 * k4v[l] + CS4 * k5[l] + CS5 * k6[l]);
    drift(y1v, k7);

    float rs[GE] = {0.f, 0.f};
#pragma unroll
    for (int l = 0; l < 2; ++l) {
      const float yerr = dtv[eh] * (CE0 * f[l] + CE2 * k3[l] + CE3 * k4v[l] + CE4 * k5[l] + CE5 * k6[l] + CE6 * k7[l]);
      const float tol = ATOL_C + RTOL_C * fmaxf(fabsf(y[l]), fabsf(y1v[l]));
      const float r = yerr / tol;
      rs[eh] += r * r;
    }
    float rsum[GE];
    blocksum(rs, rsum);

    bool acc[GE];
#pragma unroll
    for (int g = 0; g < GE; ++g)
      acc[g] = act[g] && (sqrtf(rsum[g] * (1.0f / Hd)) <= 1.0f);

    if (acc[eh]) {
#pragma unroll
      for (int l = 0; l < 2; ++l) {
        ym[l] = y[l] + dtv[eh] * (CM0 * f[l] + CM2 * k3[l] + CM3 * k4v[l] + CM4 * k5[l] + CM5 * k6[l] + CM6 * k7[l]);
        py[l] = y[l]; pf[l] = f[l];
        y[l] = y1v[l]; f[l] = k7[l];
      }
    }
#pragma unroll
    for (int g = 0; g < GE; ++g) {
      if (!act[g]) continue;
      const float er = sqrtf(rsum[g] * (1.0f / Hd));
      if (acc[g]) {
        ptv[g] = tcur[g]; pdt[g] = dtv[g];
        tcur[g] = tcur[g] + dtv[g];
      }
      float dtn;
      if (er == 0.0f) {
        dtn = dtv[g] * 10.0f;
      } else {
        const float dfac = (er < 1.0f) ? 1.0f : 0.2f;
        const float fac = fminf(10.0f, fmaxf(0.9f * powf(er, -0.2f), dfac));
        dtn = dtv[g] * fac;
      }
      dtv[g] = fmaxf(dtn, 0.0f);
      act[g] = (tcur[g] < tfin[g]) && (dtv[g] > 0.0f);
    }
  }

  // ---- interpolate at t_final (4th-order fit) and fused FC ----
  const float fcwA = fcW[jj];
  const float fcwB = fcW[j1];
  float s[GE] = {0.f, 0.f};
#pragma unroll
  for (int l = 0; l < 2; ++l) {
    const float denom = tcur[eh] - ptv[eh];
    const float xr = (tfin[eh] - ptv[eh]) / denom;
    const float dy0 = pdt[eh] * pf[l];
    const float dy1 = pdt[eh] * f[l];
    const float aa = -2.f * dy0 + 2.f * dy1 - 8.f * py[l] - 8.f * y[l] + 16.f * ym[l];
    const float bb =  5.f * dy0 - 3.f * dy1 + 18.f * py[l] + 14.f * y[l] - 32.f * ym[l];
    const float cc = -4.f * dy0 + 1.f * dy1 - 11.f * py[l] - 5.f * y[l] + 16.f * ym[l];
    const float dd = dy0;
    const float ee = py[l];
    const float yf = (((aa * xr + bb) * xr + cc) * xr + dd) * xr + ee;
    s[eh] += yf * ((l == 1) ? fcwB : fcwA);
  }
  float ssum[GE];
  blocksum(s, ssum);
  if (tid == 0) {
#pragma unroll
    for (int g = 0; g < GE; ++g) {
      float o = ssum[g] + fcb[0];
#pragma unroll
      for (int m = 0; m < MET; ++m) o += meta[(bg0 + g) * MET + m] * fcW[Hd + m];
      outp[bg0 + g] = o;
    }
  }
}

// ---------------- host launcher ----------------
extern "C" void kernel_launch(void* const* d_in, const int* in_sizes, int n_in,
                              void* d_out, int out_size, void* d_ws, size_t ws_size,
                              hipStream_t stream)
{
  (void)in_sizes; (void)n_in; (void)out_size; (void)ws_size;

  const float* x    = (const float*)d_in[0];
  const float* meta = (const float*)d_in[1];
  const float* eps  = (const float*)d_in[2];
  const float* gWih = (const float*)d_in[3];
  const float* gWhh = (const float*)d_in[4];
  const float* gbih = (const float*)d_in[5];
  const float* gbhh = (const float*)d_in[6];
  const float* eW1  = (const float*)d_in[7];
  const float* eb1  = (const float*)d_in[8];
  const float* eW2  = (const float*)d_in[9];
  const float* eb2  = (const float*)d_in[10];
  const float* oW1  = (const float*)d_in[11];
  const float* ob1  = (const float*)d_in[12];
  const float* oW2  = (const float*)d_in[13];
  const float* ob2  = (const float*)d_in[14];
  const float* fcW  = (const float*)d_in[15];
  const float* fcb  = (const float*)d_in[16];
  float* out = (float*)d_out;
  float* ws  = (float*)d_ws;

  // ws layout (floats)
  float* WhhP = ws + 0;          //  786432
  float* WihT = ws + 786432;     //   12288
  float* eW1P = ws + 798720;     //  262144
  float* eW2P = ws + 1060864;    //  524288
  float* oW1P = ws + 1585152;    //  262144
  float* oW2P = ws + 1847296;    //  262144
  float* hA   = ws + 2109440;    //  262144 (h even-t / o1)
  float* hB   = ws + 2371584;    //  262144 (h odd-t: final h / z0)
  unsigned* bar = (unsigned*)(ws + 2633728);   // 4-byte barrier counter

  pack_kT4<<<(H3d * Hd + 255) / 256, 256, 0, stream>>>(gWhh, WhhP, H3d, Hd);
  transpose_k<<<(H3d * 8 + 255) / 256, 256, 0, stream>>>(gWih, WihT, H3d, 8);
  pack_kT4<<<(Hd * Hd + 255) / 256, 256, 0, stream>>>(eW1, eW1P, Hd, Hd);
  pack_kT4<<<(1024 * Hd + 255) / 256, 256, 0, stream>>>(eW2, eW2P, 1024, Hd);
  pack_kT4<<<(Hd * Hd + 255) / 256, 256, 0, stream>>>(oW1, oW1P, Hd, Hd);
  pack_kT4<<<(Hd * Hd + 255) / 256, 256, 0, stream>>>(oW2, oW2P, Hd, Hd);
  hipMemsetAsync(bar, 0, sizeof(unsigned), stream);

  // persistent cooperative GRU, custom lightweight barrier
  {
    void* args[] = { (void*)&x, (void*)&meta, (void*)&WihT, (void*)&WhhP,
                     (void*)&gbih, (void*)&gbhh, (void*)&hA, (void*)&hB,
                     (void*)&bar };
    hipLaunchCooperativeKernel((const void*)gru_coop2_kernel,
                               dim3(256), dim3(512), args, 0, stream);
  }
  // final h (t=63, odd) is in hB
  dim3 egrid(32, 8);
  gemm_relu_kernel<<<egrid, 256, 0, stream>>>(hB, eW1P, eb1, hA);           // o1 -> hA
  enc2_z0_kernel<<<egrid, 256, 0, stream>>>(hA, eW2P, eb2, eps, hB);        // z0 -> hB
  ode_fc_kernel<<<Bsz / 2, 512, 0, stream>>>(x, meta, hB, oW1P, ob1, oW2P, ob2, fcW, fcb, out);
}

// Round 8
// 4097.191 us; speedup vs baseline: 1.0697x; 1.0697x over previous
//
#include <hip/hip_runtime.h>
#include <math.h>

// Problem dims
constexpr int Bsz  = 512;
constexpr int Nseq = 64;
constexpr int DX   = 4;
constexpr int MET  = 4;
constexpr int Hd   = 512;
constexpr int H3d  = 1536;

constexpr float RTOL_C = 1e-3f;
constexpr float ATOL_C = 1e-5f;

// ---- Dopri5 tableau (exactly as in jax.experimental.ode, f64->f32) ----
constexpr float SB10 = (float)(1.0/5.0);
constexpr float SB20 = (float)(3.0/40.0),  SB21 = (float)(9.0/40.0);
constexpr float SB30 = (float)(44.0/45.0), SB31 = (float)(-56.0/15.0), SB32 = (float)(32.0/9.0);
constexpr float SB40 = (float)(19372.0/6561.0), SB41 = (float)(-25360.0/2187.0),
                SB42 = (float)(64448.0/6561.0), SB43 = (float)(-212.0/729.0);
constexpr float SB50 = (float)(9017.0/3168.0),  SB51 = (float)(-355.0/33.0),
                SB52 = (float)(46732.0/5247.0), SB53 = (float)(49.0/176.0),
                SB54 = (float)(-5103.0/18656.0);
constexpr float CS0 = (float)(35.0/384.0), CS2 = (float)(500.0/1113.0),
                CS3 = (float)(125.0/192.0), CS4 = (float)(-2187.0/6784.0),
                CS5 = (float)(11.0/84.0);
// Shampine error coefficients (c_sol - c_star), as written in jax ode.py
constexpr float CE0 = (float)(35.0/384.0 - 1951.0/21600.0);
constexpr float CE2 = (float)(500.0/1113.0 - 22642.0/50085.0);
constexpr float CE3 = (float)(125.0/192.0 - 451.0/720.0);
constexpr float CE4 = (float)(-2187.0/6784.0 + 12231.0/42400.0);
constexpr float CE5 = (float)(11.0/84.0 - 649.0/6300.0);
constexpr float CE6 = (float)(-1.0/60.0);
// dps_c_mid for interpolation fit
constexpr float CM0 = (float)(6025192743.0/30085553152.0/2.0);
constexpr float CM2 = (float)(51252292925.0/65400821598.0/2.0);
constexpr float CM3 = (float)(-2691868925.0/45128329728.0/2.0);
constexpr float CM4 = (float)(187940372067.0/1594534317056.0/2.0);
constexpr float CM5 = (float)(-1776094331.0/19743644256.0/2.0);
constexpr float CM6 = (float)(11237099.0/235043384.0/2.0);

__device__ __forceinline__ float selu_f(float v) {
  const float scl = 1.0507009873554805f;
  const float alp = 1.6732632423543772f;
  float e = v > 0.f ? v : alp * expm1f(v);
  return scl * e;
}
__device__ __forceinline__ float sigmoid_f(float v) {
  return 1.f / (1.f + expf(-v));
}

// ---------------- fused weight repack (replaces 6 tiny launches) ----------------
// Segments (element counts):
//   [0, 786432)          gWhh (1536x512) -> WhhP pack_kT4
//   [786432, 798720)     gWih (1536x8)   -> WihT transpose
//   [798720, 1060864)    eW1  (512x512)  -> eW1P pack_kT4
//   [1060864, 1585152)   eW2  (1024x512) -> eW2P pack_kT4
//   [1585152, 1847296)   oW1  (512x512)  -> oW1P pack_kT4
//   [1847296, 2109440)   oW2  (512x512)  -> oW2P pack_kT4
__global__ __launch_bounds__(256) void pack_all_kernel(
    const float* __restrict__ gWhh, const float* __restrict__ gWih,
    const float* __restrict__ eW1,  const float* __restrict__ eW2,
    const float* __restrict__ oW1,  const float* __restrict__ oW2,
    float* __restrict__ WhhP, float* __restrict__ WihT,
    float* __restrict__ eW1P, float* __restrict__ eW2P,
    float* __restrict__ oW1P, float* __restrict__ oW2P)
{
  int i = blockIdx.x * 256 + threadIdx.x;
  if (i < 786432) {
    const int r = i >> 9, k = i & 511;
    WhhP[(k >> 2) * (H3d * 4) + r * 4 + (k & 3)] = gWhh[i];
  } else if (i < 798720) {
    const int ii = i - 786432;
    const int r = ii >> 3, c = ii & 7;
    WihT[c * H3d + r] = gWih[ii];
  } else if (i < 1060864) {
    const int ii = i - 798720;
    const int r = ii >> 9, k = ii & 511;
    eW1P[(k >> 2) * (Hd * 4) + r * 4 + (k & 3)] = eW1[ii];
  } else if (i < 1585152) {
    const int ii = i - 1060864;
    const int r = ii >> 9, k = ii & 511;
    eW2P[(k >> 2) * (1024 * 4) + r * 4 + (k & 3)] = eW2[ii];
  } else if (i < 1847296) {
    const int ii = i - 1585152;
    const int r = ii >> 9, k = ii & 511;
    oW1P[(k >> 2) * (Hd * 4) + r * 4 + (k & 3)] = oW1[ii];
  } else if (i < 2109440) {
    const int ii = i - 1847296;
    const int r = ii >> 9, k = ii & 511;
    oW2P[(k >> 2) * (Hd * 4) + r * 4 + (k & 3)] = oW2[ii];
  }
}

// ---------------- GRU step: h_out = GRUCell(xm_t, h_in) ----------------
// grid (32,8) = 256 blocks (1/CU), 1024 threads = 16 waves/CU = 4 waves/SIMD.
// Block tile: 16 batch rows x 64 j-cols; wave rw owns row rw (1 row/thread).
// Same per-CU traffic as R6 (393KB weights L1-broadcast across rows, 32KB h),
// but 2x the waves to hide L2 latency (R6 ran 2/SIMD and spent ~15us stalled).
// grid (32,8): depth-first placement gives each XCD one y (j-tile) -> 393KB
// weight slice per XCD L2. Per-(b,j) FMA chain identical -> bit-identical h.
__global__ __launch_bounds__(1024) void gru_step_kernel(
    const float* __restrict__ x, const float* __restrict__ meta,
    const float* __restrict__ WihT, const float* __restrict__ WhhP,
    const float* __restrict__ bih, const float* __restrict__ bhh,
    const float* __restrict__ h_in, float* __restrict__ h_out, int t)
{
  __shared__ __align__(16) float hs[16][Hd];     // 32 KB h tile
  const int tid = threadIdx.x;
  const int jl  = tid & 63;
  const int rw  = tid >> 6;                      // wave 0..15 -> row rw
  const int j   = blockIdx.y * 64 + jl;
  const int b0  = blockIdx.x * 16;
  const int b   = b0 + rw;

  // stage 16x512 h tile (coalesced float4, 2 per thread)
  for (int i = tid; i < 16 * Hd / 4; i += 1024)
    *(float4*)&hs[0][i * 4] = *(const float4*)&h_in[b0 * Hd + i * 4];
  __syncthreads();

  float ar = 0.f, az = 0.f, an = 0.f;
#pragma unroll 4
  for (int k4 = 0; k4 < Hd / 4; ++k4) {
    const float4 wr = *(const float4*)&WhhP[(k4 * H3d + j) * 4];
    const float4 wz = *(const float4*)&WhhP[(k4 * H3d + 512 + j) * 4];
    const float4 wn = *(const float4*)&WhhP[(k4 * H3d + 1024 + j) * 4];
    const float4 hv = *(const float4*)&hs[rw][k4 * 4];   // broadcast read
    ar += wr.x * hv.x + wr.y * hv.y + wr.z * hv.z + wr.w * hv.w;
    az += wz.x * hv.x + wz.y * hv.y + wz.z * hv.z + wz.w * hv.w;
    an += wn.x * hv.x + wn.y * hv.y + wn.z * hv.z + wn.w * hv.w;
  }

  const float bihr = bih[j], bihz = bih[512 + j], bihn = bih[1024 + j];
  const float bhhr = bhh[j], bhhz = bhh[512 + j], bhhn = bhh[1024 + j];

  const float4 xv = *(const float4*)&x[(b * Nseq + t) * DX];
  const float4 mv = *(const float4*)&meta[b * MET];
  float xm[8] = { xv.x, xv.y, xv.z, xv.w, mv.x, mv.y, mv.z, mv.w };
  float gr = bihr, gz = bihz, gn = bihn;
#pragma unroll
  for (int kk = 0; kk < 8; ++kk) {
    gr += xm[kk] * WihT[kk * H3d + j];
    gz += xm[kk] * WihT[kk * H3d + 512 + j];
    gn += xm[kk] * WihT[kk * H3d + 1024 + j];
  }
  const float r = sigmoid_f(gr + ar + bhhr);
  const float z = sigmoid_f(gz + az + bhhz);
  const float n = tanhf(gn + r * (an + bhhn));
  const float hold = hs[rw][j];
  h_out[b * Hd + j] = (1.f - z) * n + z * hold;
}

// ---------------- encoder layer 1: relu(A @ W^T + b) ----------------
__global__ __launch_bounds__(256) void gemm_relu_kernel(
    const float* __restrict__ A, const float* __restrict__ WP,
    const float* __restrict__ bias, float* __restrict__ Cout)
{
  __shared__ __align__(16) float as[16 * Hd];
  const int tid  = threadIdx.x;
  const int jl   = tid & 63;
  const int bsub = tid >> 6;
  const int j    = blockIdx.y * 64 + jl;
  const int b0   = blockIdx.x * 16;

  for (int i = tid; i < 16 * Hd; i += 256) as[i] = A[b0 * Hd + i];
  __syncthreads();

  float acc[4] = {0.f, 0.f, 0.f, 0.f};
#pragma unroll 2
  for (int k4 = 0; k4 < Hd / 4; ++k4) {
    const float4 w = *(const float4*)&WP[(k4 * Hd + j) * 4];
#pragma unroll
    for (int m = 0; m < 4; ++m) {
      const float4 av = *(const float4*)&as[(bsub * 4 + m) * Hd + k4 * 4];
      acc[m] += w.x * av.x + w.y * av.y + w.z * av.z + w.w * av.w;
    }
  }
  const float bj = bias[j];
#pragma unroll
  for (int m = 0; m < 4; ++m) {
    const int b = b0 + bsub * 4 + m;
    float v = acc[m] + bj;
    Cout[b * Hd + j] = v > 0.f ? v : 0.f;
  }
}

// ---------------- encoder layer 2 + reparam: z0 = eps*std + mean ----------------
__global__ __launch_bounds__(256) void enc2_z0_kernel(
    const float* __restrict__ O1, const float* __restrict__ W2P,  // [k4][1024][4]
    const float* __restrict__ b2, const float* __restrict__ eps,
    float* __restrict__ z0)
{
  __shared__ __align__(16) float as[16 * Hd];
  const int tid  = threadIdx.x;
  const int jl   = tid & 63;
  const int bsub = tid >> 6;
  const int j    = blockIdx.y * 64 + jl;
  const int b0   = blockIdx.x * 16;

  for (int i = tid; i < 16 * Hd; i += 256) as[i] = O1[b0 * Hd + i];
  __syncthreads();

  float am[4] = {0.f, 0.f, 0.f, 0.f};
  float asd[4] = {0.f, 0.f, 0.f, 0.f};
#pragma unroll 2
  for (int k4 = 0; k4 < Hd / 4; ++k4) {
    const float4 wm = *(const float4*)&W2P[(k4 * 1024 + j) * 4];
    const float4 ws = *(const float4*)&W2P[(k4 * 1024 + 512 + j) * 4];
#pragma unroll
    for (int m = 0; m < 4; ++m) {
      const float4 av = *(const float4*)&as[(bsub * 4 + m) * Hd + k4 * 4];
      am[m]  += wm.x * av.x + wm.y * av.y + wm.z * av.z + wm.w * av.w;
      asd[m] += ws.x * av.x + ws.y * av.y + ws.z * av.z + ws.w * av.w;
    }
  }
  const float bm = b2[j], bs = b2[512 + j];
#pragma unroll
  for (int m = 0; m < 4; ++m) {
    const int b = b0 + bsub * 4 + m;
    const float mean = am[m] + bm;
    const float sd   = asd[m] + bs;
    z0[b * Hd + j] = eps[b * Hd + j] * sd + mean;
  }
}

// ---------------- adaptive Dopri5 ODE solve + final FC ----------------
// 256 blocks x 512 threads, GE=2. At ~89% of the per-CU L1-fill floor
// (2MB W1+W2 per drift through each CU's L1 ~= 13.4us vs 15.4 measured).
// GE-invariant floor (every CU computing a drift streams the full 2MB),
// so structure is final for this decomposition.
__global__ __launch_bounds__(512) void ode_fc_kernel(
    const float* __restrict__ x, const float* __restrict__ meta,
    const float* __restrict__ z0in,
    const float* __restrict__ W1P, const float* __restrict__ b1v,
    const float* __restrict__ W2P, const float* __restrict__ b2v,
    const float* __restrict__ fcW, const float* __restrict__ fcb,
    float* __restrict__ outp)
{
  constexpr int GE = 2;
  __shared__ __align__(16) float zsh[GE][Hd];   // 4 KB
  __shared__ float red[8 * GE];
  const int tid = threadIdx.x;
  const int jj  = tid & 255;
  const int eh  = tid >> 8;            // element 0/1 (wave-uniform)
  const int j1  = jj + 256;
  const int bg0 = blockIdx.x * GE;

  const float b1a = b1v[jj], b1b = b1v[j1];
  const float b2a = b2v[jj], b2b = b2v[j1];

  // drift for the thread's 2 (j, eh) slots
  auto drift = [&](const float (&in)[2], float (&out)[2]) {
    __syncthreads();
    zsh[eh][jj] = in[0];
    zsh[eh][j1] = in[1];
    __syncthreads();
    float u0 = b1a, u1 = b1b;
#pragma unroll 4
    for (int k4 = 0; k4 < Hd / 4; ++k4) {
      const float4 wA = *(const float4*)&W1P[(k4 * Hd + jj) * 4];
      const float4 wB = *(const float4*)&W1P[(k4 * Hd + j1) * 4];
      const float4 z  = *(const float4*)&zsh[eh][k4 * 4];
      u0 += wA.x * z.x + wA.y * z.y + wA.z * z.z + wA.w * z.w;
      u1 += wB.x * z.x + wB.y * z.y + wB.z * z.z + wB.w * z.w;
    }
    u0 = selu_f(u0); u1 = selu_f(u1);
    __syncthreads();
    zsh[eh][jj] = u0;
    zsh[eh][j1] = u1;
    __syncthreads();
    float v0 = b2a, v1 = b2b;
#pragma unroll 4
    for (int k4 = 0; k4 < Hd / 4; ++k4) {
      const float4 wA = *(const float4*)&W2P[(k4 * Hd + jj) * 4];
      const float4 wB = *(const float4*)&W2P[(k4 * Hd + j1) * 4];
      const float4 z  = *(const float4*)&zsh[eh][k4 * 4];
      v0 += wA.x * z.x + wA.y * z.y + wA.z * z.z + wA.w * z.w;
      v1 += wB.x * z.x + wB.y * z.y + wB.z * z.z + wB.w * z.w;
    }
    out[0] = v0; out[1] = v1;
  };

  // block-wide per-element sum; all threads receive identical results
  auto blocksum = [&](float (&v)[GE], float (&s)[GE]) {
#pragma unroll
    for (int off = 32; off > 0; off >>= 1) {
#pragma unroll
      for (int g = 0; g < GE; ++g) v[g] += __shfl_down(v[g], off);
    }
    __syncthreads();
    if ((tid & 63) == 0) {
      const int w = tid >> 6;
#pragma unroll
      for (int g = 0; g < GE; ++g) red[w * GE + g] = v[g];
    }
    __syncthreads();
#pragma unroll
    for (int g = 0; g < GE; ++g) {
      float t = 0.f;
#pragma unroll
      for (int w = 0; w < 8; ++w) t += red[w * GE + g];
      s[g] = t;
    }
  };

  float y[2], f[2], py[2], pf[2], ym[2];
  float tcur[GE], dtv[GE], tfin[GE], ptv[GE], pdt[GE];
  bool act[GE];

  y[0] = z0in[(bg0 + eh) * Hd + jj];
  y[1] = z0in[(bg0 + eh) * Hd + j1];
#pragma unroll
  for (int g = 0; g < GE; ++g) {
    tcur[g] = x[((bg0 + g) * Nseq + 0) * DX];
    tfin[g] = x[((bg0 + g) * Nseq + (Nseq - 1)) * DX];
  }

  drift(y, f);

  // ---- initial step size (Hairer / jax variant) ----
  float sc[2];
  float q0[GE] = {0.f, 0.f}, q1[GE] = {0.f, 0.f};
#pragma unroll
  for (int l = 0; l < 2; ++l) {
    sc[l] = ATOL_C + RTOL_C * fabsf(y[l]);
    const float a = y[l] / sc[l], b = f[l] / sc[l];
    q0[eh] += a * a;
    q1[eh] += b * b;
  }
  float d0s[GE], d1s[GE];
  blocksum(q0, d0s);
  blocksum(q1, d1s);
  float h0[GE];
#pragma unroll
  for (int g = 0; g < GE; ++g) {
    const float d0 = sqrtf(d0s[g]), d1 = sqrtf(d1s[g]);
    h0[g] = (d0 < 1e-5f || d1 < 1e-5f) ? 1e-6f : 0.01f * d0 / d1;
  }
  float yin[2], f1h[2];
#pragma unroll
  for (int l = 0; l < 2; ++l) yin[l] = y[l] + h0[eh] * f[l];
  drift(yin, f1h);
  float q2[GE] = {0.f, 0.f};
#pragma unroll
  for (int l = 0; l < 2; ++l) {
    const float dd = (f1h[l] - f[l]) / sc[l];
    q2[eh] += dd * dd;
  }
  float d2s[GE];
  blocksum(q2, d2s);
#pragma unroll
  for (int g = 0; g < GE; ++g) {
    const float d1 = sqrtf(d1s[g]);
    const float d2 = sqrtf(d2s[g]) / h0[g];
    const float h1 = (d1 <= 1e-15f && d2 <= 1e-15f)
                 ? fmaxf(1e-6f, h0[g] * 1e-3f)
                 : powf(0.01f / (d1 + d2), 0.2f);   // jax uses d1+d2 here
    dtv[g] = fminf(100.f * h0[g], h1);
    ptv[g] = tcur[g]; pdt[g] = dtv[g];
    act[g] = (tcur[g] < tfin[g]) && (dtv[g] > 0.f);
  }
#pragma unroll
  for (int l = 0; l < 2; ++l) { py[l] = y[l]; pf[l] = f[l]; ym[l] = y[l]; }

  // ---- adaptive stepping loop ----
  float k2[2], k3[2], k4v[2], k5[2], k6[2], k7[2], y1v[2];
  for (int iter = 0; iter < 4000; ++iter) {
    if (!(act[0] || act[1])) break;

#pragma unroll
    for (int l = 0; l < 2; ++l) yin[l] = y[l] + dtv[eh] * (SB10 * f[l]);
    drift(yin, k2);

#pragma unroll
    for (int l = 0; l < 2; ++l)
      yin[l] = y[l] + dtv[eh] * (SB20 * f[l] + SB21 * k2[l]);
    drift(yin, k3);

#pragma unroll
    for (int l = 0; l < 2; ++l)
      yin[l] = y[l] + dtv[eh] * (SB30 * f[l] + SB31 * k2[l] + SB32 * k3[l]);
    drift(yin, k4v);

#pragma unroll
    for (int l = 0; l < 2; ++l)
      yin[l] = y[l] + dtv[eh] * (SB40 * f[l] + SB41 * k2[l] + SB42 * k3[l] + SB43 * k4v[l]);
    drift(yin, k5);

#pragma unroll
    for (int l = 0; l < 2; ++l)
      yin[l] = y[l] + dtv[eh] * (SB50 * f[l] + SB51 * k2[l] + SB52 * k3[l] + SB53 * k4v[l] + SB54 * k5[l]);
    drift(yin, k6);

#pragma unroll
    for (int l = 0; l < 2; ++l)
      y1v[l] = y[l] + dtv[eh] * (CS0 * f[l] + CS2 * k3[l] + CS3 * k4v[l] + CS4 * k5[l] + CS5 * k6[l]);
    drift(y1v, k7);

    float rs[GE] = {0.f, 0.f};
#pragma unroll
    for (int l = 0; l < 2; ++l) {
      const float yerr = dtv[eh] * (CE0 * f[l] + CE2 * k3[l] + CE3 * k4v[l] + CE4 * k5[l] + CE5 * k6[l] + CE6 * k7[l]);
      const float tol = ATOL_C + RTOL_C * fmaxf(fabsf(y[l]), fabsf(y1v[l]));
      const float r = yerr / tol;
      rs[eh] += r * r;
    }
    float rsum[GE];
    blocksum(rs, rsum);

    bool acc[GE];
#pragma unroll
    for (int g = 0; g < GE; ++g)
      acc[g] = act[g] && (sqrtf(rsum[g] * (1.0f / Hd)) <= 1.0f);

    if (acc[eh]) {
#pragma unroll
      for (int l = 0; l < 2; ++l) {
        ym[l] = y[l] + dtv[eh] * (CM0 * f[l] + CM2 * k3[l] + CM3 * k4v[l] + CM4 * k5[l] + CM5 * k6[l] + CM6 * k7[l]);
        py[l] = y[l]; pf[l] = f[l];
        y[l] = y1v[l]; f[l] = k7[l];
      }
    }
#pragma unroll
    for (int g = 0; g < GE; ++g) {
      if (!act[g]) continue;
      const float er = sqrtf(rsum[g] * (1.0f / Hd));
      if (acc[g]) {
        ptv[g] = tcur[g]; pdt[g] = dtv[g];
        tcur[g] = tcur[g] + dtv[g];
      }
      float dtn;
      if (er == 0.0f) {
        dtn = dtv[g] * 10.0f;
      } else {
        const float dfac = (er < 1.0f) ? 1.0f : 0.2f;
        const float fac = fminf(10.0f, fmaxf(0.9f * powf(er, -0.2f), dfac));
        dtn = dtv[g] * fac;
      }
      dtv[g] = fmaxf(dtn, 0.0f);
      act[g] = (tcur[g] < tfin[g]) && (dtv[g] > 0.0f);
    }
  }

  // ---- interpolate at t_final (4th-order fit) and fused FC ----
  const float fcwA = fcW[jj];
  const float fcwB = fcW[j1];
  float s[GE] = {0.f, 0.f};
#pragma unroll
  for (int l = 0; l < 2; ++l) {
    const float denom = tcur[eh] - ptv[eh];
    const float xr = (tfin[eh] - ptv[eh]) / denom;
    const float dy0 = pdt[eh] * pf[l];
    const float dy1 = pdt[eh] * f[l];
    const float aa = -2.f * dy0 + 2.f * dy1 - 8.f * py[l] - 8.f * y[l] + 16.f * ym[l];
    const float bb =  5.f * dy0 - 3.f * dy1 + 18.f * py[l] + 14.f * y[l] - 32.f * ym[l];
    const float cc = -4.f * dy0 + 1.f * dy1 - 11.f * py[l] - 5.f * y[l] + 16.f * ym[l];
    const float dd = dy0;
    const float ee = py[l];
    const float yf = (((aa * xr + bb) * xr + cc) * xr + dd) * xr + ee;
    s[eh] += yf * ((l == 1) ? fcwB : fcwA);
  }
  float ssum[GE];
  blocksum(s, ssum);
  if (tid == 0) {
#pragma unroll
    for (int g = 0; g < GE; ++g) {
      float o = ssum[g] + fcb[0];
#pragma unroll
      for (int m = 0; m < MET; ++m) o += meta[(bg0 + g) * MET + m] * fcW[Hd + m];
      outp[bg0 + g] = o;
    }
  }
}

// ---------------- host launcher ----------------
extern "C" void kernel_launch(void* const* d_in, const int* in_sizes, int n_in,
                              void* d_out, int out_size, void* d_ws, size_t ws_size,
                              hipStream_t stream)
{
  (void)in_sizes; (void)n_in; (void)out_size; (void)ws_size;

  const float* x    = (const float*)d_in[0];
  const float* meta = (const float*)d_in[1];
  const float* eps  = (const float*)d_in[2];
  const float* gWih = (const float*)d_in[3];
  const float* gWhh = (const float*)d_in[4];
  const float* gbih = (const float*)d_in[5];
  const float* gbhh = (const float*)d_in[6];
  const float* eW1  = (const float*)d_in[7];
  const float* eb1  = (const float*)d_in[8];
  const float* eW2  = (const float*)d_in[9];
  const float* eb2  = (const float*)d_in[10];
  const float* oW1  = (const float*)d_in[11];
  const float* ob1  = (const float*)d_in[12];
  const float* oW2  = (const float*)d_in[13];
  const float* ob2  = (const float*)d_in[14];
  const float* fcW  = (const float*)d_in[15];
  const float* fcb  = (const float*)d_in[16];
  float* out = (float*)d_out;
  float* ws  = (float*)d_ws;

  // ws layout (floats)
  float* WhhP = ws + 0;          //  786432
  float* WihT = ws + 786432;     //   12288
  float* eW1P = ws + 798720;     //  262144
  float* eW2P = ws + 1060864;    //  524288
  float* oW1P = ws + 1585152;    //  262144
  float* oW2P = ws + 1847296;    //  262144
  float* hA   = ws + 2109440;    //  262144 (h ping / z0)
  float* hB   = ws + 2371584;    //  262144 (h pong / o1)

  // all 6 weight repacks in one launch (2109440 elements)
  pack_all_kernel<<<(2109440 + 255) / 256, 256, 0, stream>>>(
      gWhh, gWih, eW1, eW2, oW1, oW2, WhhP, WihT, eW1P, eW2P, oW1P, oW2P);
  hipMemsetAsync(hA, 0, (size_t)Bsz * Hd * sizeof(float), stream);

  // per-step GRU: 256 blocks x 1024 threads (16 waves/CU = 4/SIMD)
  dim3 ggrid(32, 8);
  for (int t = 0; t < Nseq; ++t) {
    const float* hin = (t & 1) ? hB : hA;
    float* hout      = (t & 1) ? hA : hB;
    gru_step_kernel<<<ggrid, 1024, 0, stream>>>(x, meta, WihT, WhhP, gbih, gbhh, hin, hout, t);
  }
  // final h in hA (t=63 odd writes hA)
  dim3 egrid(32, 8);
  gemm_relu_kernel<<<egrid, 256, 0, stream>>>(hA, eW1P, eb1, hB);           // o1 -> hB
  enc2_z0_kernel<<<egrid, 256, 0, stream>>>(hB, eW2P, eb2, eps, hA);        // z0 -> hA
  ode_fc_kernel<<<Bsz / 2, 512, 0, stream>>>(x, meta, hA, oW1P, ob1, oW2P, ob2, fcW, fcb, out);
}